// Round 2
// baseline (538.597 us; speedup 1.0000x reference)
//
#include <hip/hip_runtime.h>
#include <stdint.h>

// Problem constants (reference: B=8, Q=2048, K=2048, D=512)
#define BB 8
#define QQ 2048
#define KK 2048
#define DD 512

typedef _Float16 f16x8 __attribute__((ext_vector_type(8)));
typedef float f32x4 __attribute__((ext_vector_type(4)));

__device__ __forceinline__ unsigned short f2h(float f) {
    union { _Float16 h; unsigned short u; } x;
    x.h = (_Float16)f;
    return x.u;
}
__device__ __forceinline__ float h2f(unsigned short u) {
    union { unsigned short u; _Float16 h; } x;
    x.u = u;
    return (float)x.h;
}

// async global->LDS, 16 B per lane; lds is wave-uniform base, HW scatters
// lane l to lds + l*16 (m97/m104 semantics).
__device__ __forceinline__ void async16(const unsigned short* g, unsigned short* l) {
    __builtin_amdgcn_global_load_lds(
        (const __attribute__((address_space(1))) unsigned int*)g,
        (__attribute__((address_space(3))) unsigned int*)l, 16, 0, 0);
}

// ---------------------------------------------------------------------------
// fp32 -> fp16 convert, 8 elems/thread
// ---------------------------------------------------------------------------
__global__ __launch_bounds__(256) void cvt_f32_f16(const float* __restrict__ in,
                                                   unsigned short* __restrict__ out) {
    size_t i = ((size_t)blockIdx.x * 256 + threadIdx.x) * 8;
    float4 a = *(const float4*)(in + i);
    float4 b = *(const float4*)(in + i + 4);
    uint4 u;
    u.x = (unsigned)f2h(a.x) | ((unsigned)f2h(a.y) << 16);
    u.y = (unsigned)f2h(a.z) | ((unsigned)f2h(a.w) << 16);
    u.z = (unsigned)f2h(b.x) | ((unsigned)f2h(b.y) << 16);
    u.w = (unsigned)f2h(b.z) | ((unsigned)f2h(b.w) << 16);
    *(uint4*)(out + i) = u;
}

// ---------------------------------------------------------------------------
// Tiled transpose + convert: in[R][C] fp32 -> out[C][R] fp16 (32x32 tiles)
// ---------------------------------------------------------------------------
__global__ __launch_bounds__(256) void transpose_cvt(const float* __restrict__ in,
                                                     unsigned short* __restrict__ out,
                                                     int R, int C, long inB, long outB) {
    __shared__ float t[32][33];
    const float* ip = in + (size_t)blockIdx.z * inB;
    unsigned short* op = out + (size_t)blockIdx.z * outB;
    int x = threadIdx.x & 31, y0 = threadIdx.x >> 5;   // 32 x 8
    int c0 = blockIdx.x * 32, r0 = blockIdx.y * 32;
#pragma unroll
    for (int i = 0; i < 32; i += 8)
        t[y0 + i][x] = ip[(size_t)(r0 + y0 + i) * C + c0 + x];
    __syncthreads();
#pragma unroll
    for (int i = 0; i < 32; i += 8)
        op[(size_t)(c0 + y0 + i) * R + r0 + x] = f2h(t[x][y0 + i]);
}

// ---------------------------------------------------------------------------
// NT GEMM: C[m,n] = sum_k A[m,k]*B[n,k], 128x128 tile, BK=32, f16 MFMA,
// async global_load_lds staging on both operands.
// All variants use a bijective XCD-aware work swizzle (T1, m204 form) so
// consecutive work items (which share the A row-panel; x is fastest) land on
// the same XCD's L2.
// OUTM 0: plain f16 out (qW)
// OUTM 1: expS epilogue: e = mask ? exp(acc*scale) : 0 -> f16 out,
//         per-row sums accumulated into `sums` via atomicAdd (scores)
// OUTM 2: fp32 out, scaled by 1/sums[row]  (context)  +  FUSED dist write:
//         while the Sc A-tile sits in LDS each K-step, each n-block writes its
//         1/gridDim.x slice of dist[row, kk..] = Sc * (1/sums[row]) as fp32
//         (replaces the separate normalize_rows pass).
// ---------------------------------------------------------------------------
template <int OUTM>
__global__ __launch_bounds__(256) void gemm_bt(const unsigned short* __restrict__ Aall,
                                               const unsigned short* __restrict__ Ball,
                                               void* __restrict__ Call,
                                               const int* __restrict__ maskAll,
                                               float* __restrict__ sums,
                                               float* __restrict__ distOut,
                                               int Kred, int lda, int ldb, int ldc,
                                               long aStride, long bStride, long cStride,
                                               int maskStride, float scale) {
    // ---- bijective XCD swizzle: hardware order p -> work id w ----
    const int gx = gridDim.x, gy = gridDim.y;
    const int nwg = gx * gy * (int)gridDim.z;
    const int p = ((int)blockIdx.z * gy + (int)blockIdx.y) * gx + (int)blockIdx.x;
    const int qch = nwg >> 3, rch = nwg & 7;
    const int xcd = p & 7, ooff = p >> 3;
    const int w = (xcd < rch ? xcd * (qch + 1) : rch * (qch + 1) + (xcd - rch) * qch) + ooff;
    const int b = w / (gx * gy);
    const int rem = w - b * (gx * gy);
    const int my = rem / gx;
    const int nx = rem - my * gx;
    const int m0 = my * 128;
    const int n0 = nx * 128;

    __shared__ unsigned short As[128 * 32];
    __shared__ unsigned short Bs[128 * 32];

    const int tid = threadIdx.x;
    const int lane = tid & 63, wave = tid >> 6;
    const int wm = wave >> 1, wn = wave & 1;
    const int lrow = lane & 15, quad = lane >> 4;

    // async staging: call j covers rows j*64 + tid>>2, col (tid&3)*8 (16 B)
    const int ar = tid >> 2, ac = (tid & 3) * 8;

    const unsigned short* Ab = Aall + (size_t)b * aStride + (size_t)m0 * lda;
    const unsigned short* Bb = Ball + (size_t)b * bStride + (size_t)n0 * ldb;
    unsigned short* AsW = As + wave * 512;   // wave-uniform async dst
    unsigned short* BsW = Bs + wave * 512;

    // fused-dist setup (OUTM==2 only): thread t owns row tid>>1, 16 cols
    float invRow = 0.f;
    const unsigned short* dsrc = nullptr;
    float* dp = nullptr;
    int dklo = 0, dkhi = 0;
    if constexpr (OUTM == 2) {
        const int drow = tid >> 1, dcol = (tid & 1) * 16;
        invRow = 1.0f / sums[(size_t)b * QQ + m0 + drow];
        dsrc = As + drow * 32 + dcol;
        dp = distOut + (size_t)b * QQ * KK + (size_t)(m0 + drow) * KK + dcol;
        const int kper = Kred / gx;          // this n-block's K-slice of dist
        dklo = nx * kper;
        dkhi = dklo + kper;
    }

    f32x4 acc[4][4];
#pragma unroll
    for (int mi = 0; mi < 4; mi++)
#pragma unroll
        for (int ni = 0; ni < 4; ni++)
            acc[mi][ni] = (f32x4){0.f, 0.f, 0.f, 0.f};

    for (int kk = 0; kk < Kred; kk += 32) {
#pragma unroll
        for (int j = 0; j < 2; j++)
            async16(Ab + (size_t)(j * 64 + ar) * lda + kk + ac, AsW + j * 2048);
#pragma unroll
        for (int j = 0; j < 2; j++)
            async16(Bb + (size_t)(j * 64 + ar) * ldb + kk + ac, BsW + j * 2048);
        __syncthreads();

        f16x8 af[4], bfr[4];
#pragma unroll
        for (int i = 0; i < 4; i++)
            af[i] = *(const f16x8*)&As[(wm * 64 + i * 16 + lrow) * 32 + quad * 8];
#pragma unroll
        for (int i = 0; i < 4; i++)
            bfr[i] = *(const f16x8*)&Bs[(wn * 64 + i * 16 + lrow) * 32 + quad * 8];

#pragma unroll
        for (int mi = 0; mi < 4; mi++)
#pragma unroll
            for (int ni = 0; ni < 4; ni++)
                acc[mi][ni] = __builtin_amdgcn_mfma_f32_16x16x32_f16(af[mi], bfr[ni],
                                                                     acc[mi][ni], 0, 0, 0);

        // fused dist write: Sc tile is live in As between the two barriers
        if constexpr (OUTM == 2) {
            if (kk >= dklo && kk < dkhi) {
                f16x8 h0 = *(const f16x8*)dsrc;
                f16x8 h1 = *(const f16x8*)(dsrc + 8);
                float vals[16];
#pragma unroll
                for (int i = 0; i < 8; i++) vals[i] = (float)h0[i] * invRow;
#pragma unroll
                for (int i = 0; i < 8; i++) vals[8 + i] = (float)h1[i] * invRow;
#pragma unroll
                for (int i = 0; i < 4; i++) {
                    f32x4 o = {vals[4 * i], vals[4 * i + 1], vals[4 * i + 2], vals[4 * i + 3]};
                    __builtin_nontemporal_store(o, (f32x4*)(dp + kk + 4 * i));
                }
            }
        }
        __syncthreads();
    }

    // ---- epilogue ----
#pragma unroll
    for (int mi = 0; mi < 4; mi++) {
        const int gm = m0 + wm * 64 + mi * 16 + quad * 4;
        if constexpr (OUTM == 0) {
            unsigned short* C = (unsigned short*)Call + (size_t)b * cStride;
#pragma unroll
            for (int ni = 0; ni < 4; ni++) {
                int gn = n0 + wn * 64 + ni * 16 + lrow;
#pragma unroll
                for (int r = 0; r < 4; r++)
                    C[(size_t)(gm + r) * ldc + gn] = f2h(acc[mi][ni][r]);
            }
        } else if constexpr (OUTM == 1) {
            unsigned short* C = (unsigned short*)Call + (size_t)b * cStride;
            const int* mk = maskAll + (size_t)b * maskStride;
            float ps[4] = {0.f, 0.f, 0.f, 0.f};
#pragma unroll
            for (int ni = 0; ni < 4; ni++) {
                int gn = n0 + wn * 64 + ni * 16 + lrow;
                bool keep = mk[gn] != 0;
#pragma unroll
                for (int r = 0; r < 4; r++) {
                    float e = keep ? __expf(acc[mi][ni][r] * scale) : 0.f;
                    C[(size_t)(gm + r) * ldc + gn] = f2h(e);
                    ps[r] += e;
                }
            }
            // reduce across the 16 lanes sharing this quad's rows
#pragma unroll
            for (int off = 1; off < 16; off <<= 1)
#pragma unroll
                for (int r = 0; r < 4; r++) ps[r] += __shfl_xor(ps[r], off);
            if (lrow == 0) {
                float* s = sums + (size_t)b * QQ;
#pragma unroll
                for (int r = 0; r < 4; r++) atomicAdd(&s[gm + r], ps[r]);
            }
        } else {
            float* C = (float*)Call + (size_t)b * cStride;
            const float* s = sums + (size_t)b * QQ;
            float iv[4];
#pragma unroll
            for (int r = 0; r < 4; r++) iv[r] = 1.0f / s[gm + r];
#pragma unroll
            for (int ni = 0; ni < 4; ni++) {
                int gn = n0 + wn * 64 + ni * 16 + lrow;
#pragma unroll
                for (int r = 0; r < 4; r++)
                    C[(size_t)(gm + r) * ldc + gn] = acc[mi][ni][r] * iv[r];
            }
        }
    }
}

// ---------------------------------------------------------------------------
extern "C" void kernel_launch(void* const* d_in, const int* in_sizes, int n_in,
                              void* d_out, int out_size, void* d_ws, size_t ws_size,
                              hipStream_t stream) {
    const float* q    = (const float*)d_in[0];   // [B,Q,D]
    const float* k    = (const float*)d_in[1];   // [B,K,D]
    const float* v    = (const float*)d_in[2];   // [B,K,D]
    const int*   mask = (const int*)d_in[3];     // [B,K]
    const float* W    = (const float*)d_in[4];   // [D,D]

    float* ctx  = (float*)d_out;                           // [B,Q,D]
    float* dist = ctx + (size_t)BB * QQ * DD;              // [B,Q,K]

    // workspace layout (f16 = unsigned short), ~135 MiB
    unsigned short* ws  = (unsigned short*)d_ws;
    unsigned short* Wt  = ws;                                   // [D][D]   (W^T)
    unsigned short* Qh  = Wt + (size_t)DD * DD;                 // [B][Q][D]
    unsigned short* Kh  = Qh + (size_t)BB * QQ * DD;            // [B][K][D]
    unsigned short* Vt  = Kh + (size_t)BB * KK * DD;            // [B][D][K] (V^T)
    unsigned short* qWh = Vt + (size_t)BB * DD * KK;            // [B][Q][D]
    unsigned short* Sc  = qWh + (size_t)BB * QQ * DD;           // [B][Q][K] expS f16
    float* sums = (float*)(Sc + (size_t)BB * QQ * KK);          // [B][Q]

    const float scale = 0.044194173824159216f;  // 1/sqrt(512)

    // 0) zero the row-sum accumulators (graph-capture-legal async memset)
    (void)hipMemsetAsync(sums, 0, (size_t)BB * QQ * sizeof(float), stream);
    // 1) W -> W^T f16
    transpose_cvt<<<dim3(DD / 32, DD / 32, 1), 256, 0, stream>>>(W, Wt, DD, DD, 0, 0);
    // 2) query, key -> f16
    cvt_f32_f16<<<dim3((BB * QQ * DD / 8) / 256), 256, 0, stream>>>(q, Qh);
    cvt_f32_f16<<<dim3((BB * KK * DD / 8) / 256), 256, 0, stream>>>(k, Kh);
    // 3) value -> V^T f16
    transpose_cvt<<<dim3(DD / 32, KK / 32, BB), 256, 0, stream>>>(
        v, Vt, KK, DD, (long)KK * DD, (long)DD * KK);
    // 4) qW[b] = Q[b] @ W: M=Q, N=D, Kred=D -> f16
    gemm_bt<0><<<dim3(DD / 128, QQ / 128, BB), 256, 0, stream>>>(
        Qh, Wt, qWh, nullptr, nullptr, nullptr, DD, DD, DD, DD,
        (long)QQ * DD, 0, (long)QQ * DD, 0, 0.f);
    // 5) expS[b] = exp(scale * qW[b] @ key[b]^T) (masked->0) + row sums
    gemm_bt<1><<<dim3(KK / 128, QQ / 128, BB), 256, 0, stream>>>(
        qWh, Kh, Sc, mask, sums, nullptr, DD, DD, DD, KK,
        (long)QQ * DD, (long)KK * DD, (long)QQ * KK, KK, scale);
    // 6+7) context[b] = (expS[b] @ value[b]) / rowsum, with fused
    //      dist = expS/rowsum written from the staged LDS tiles.
    gemm_bt<2><<<dim3(DD / 128, QQ / 128, BB), 256, 0, stream>>>(
        Sc, Vt, ctx, nullptr, sums, dist, KK, KK, KK, DD,
        (long)QQ * KK, (long)DD * KK, (long)QQ * DD, 0, 0.f);
}

// Round 3
// 422.292 us; speedup vs baseline: 1.2754x; 1.2754x over previous
//
#include <hip/hip_runtime.h>
#include <stdint.h>

// Problem constants (reference: B=8, Q=2048, K=2048, D=512)
#define BB 8
#define QQ 2048
#define KK 2048
#define DD 512

typedef _Float16 f16x8 __attribute__((ext_vector_type(8)));
typedef float f32x4 __attribute__((ext_vector_type(4)));

__device__ __forceinline__ unsigned short f2h(float f) {
    union { _Float16 h; unsigned short u; } x;
    x.h = (_Float16)f;
    return x.u;
}
__device__ __forceinline__ float h2f(unsigned short u) {
    union { unsigned short u; _Float16 h; } x;
    x.u = u;
    return (float)x.h;
}

// async global->LDS, 16 B per lane; lds is wave-uniform base, HW scatters
// lane l to lds + l*16 (m97/m104 semantics).
__device__ __forceinline__ void async16(const unsigned short* g, unsigned short* l) {
    __builtin_amdgcn_global_load_lds(
        (const __attribute__((address_space(1))) unsigned int*)g,
        (__attribute__((address_space(3))) unsigned int*)l, 16, 0, 0);
}

// ---------------------------------------------------------------------------
// fp32 -> fp16 convert, 8 elems/thread
// ---------------------------------------------------------------------------
__global__ __launch_bounds__(256) void cvt_f32_f16(const float* __restrict__ in,
                                                   unsigned short* __restrict__ out) {
    size_t i = ((size_t)blockIdx.x * 256 + threadIdx.x) * 8;
    float4 a = *(const float4*)(in + i);
    float4 b = *(const float4*)(in + i + 4);
    uint4 u;
    u.x = (unsigned)f2h(a.x) | ((unsigned)f2h(a.y) << 16);
    u.y = (unsigned)f2h(a.z) | ((unsigned)f2h(a.w) << 16);
    u.z = (unsigned)f2h(b.x) | ((unsigned)f2h(b.y) << 16);
    u.w = (unsigned)f2h(b.z) | ((unsigned)f2h(b.w) << 16);
    *(uint4*)(out + i) = u;
}

// ---------------------------------------------------------------------------
// Tiled transpose + convert: in[R][C] fp32 -> out[C][R] fp16 (32x32 tiles)
// ---------------------------------------------------------------------------
__global__ __launch_bounds__(256) void transpose_cvt(const float* __restrict__ in,
                                                     unsigned short* __restrict__ out,
                                                     int R, int C, long inB, long outB) {
    __shared__ float t[32][33];
    const float* ip = in + (size_t)blockIdx.z * inB;
    unsigned short* op = out + (size_t)blockIdx.z * outB;
    int x = threadIdx.x & 31, y0 = threadIdx.x >> 5;   // 32 x 8
    int c0 = blockIdx.x * 32, r0 = blockIdx.y * 32;
#pragma unroll
    for (int i = 0; i < 32; i += 8)
        t[y0 + i][x] = ip[(size_t)(r0 + y0 + i) * C + c0 + x];
    __syncthreads();
#pragma unroll
    for (int i = 0; i < 32; i += 8)
        op[(size_t)(c0 + y0 + i) * R + r0 + x] = f2h(t[x][y0 + i]);
}

// ---------------------------------------------------------------------------
// NT GEMM: C[m,n] = sum_k A[m,k]*B[n,k], 128x128 tile, BK=32, f16 MFMA,
// async global_load_lds staging on both operands.
// Bijective XCD-aware work swizzle (T1, m204 form): consecutive work items
// (sharing the A row-panel; x fastest) land on the same XCD's L2.
// OUTM 0: plain f16 out (qW)
// OUTM 1: expS epilogue: e = mask ? exp(acc*scale) : 0 -> f16 out,
//         per-row sums accumulated into `sums` via atomicAdd (scores)
// OUTM 2: fp32 out, scaled by 1/sums[row]  (context)
// ---------------------------------------------------------------------------
template <int OUTM>
__global__ __launch_bounds__(256) void gemm_bt(const unsigned short* __restrict__ Aall,
                                               const unsigned short* __restrict__ Ball,
                                               void* __restrict__ Call,
                                               const int* __restrict__ maskAll,
                                               float* __restrict__ sums,
                                               int Kred, int lda, int ldb, int ldc,
                                               long aStride, long bStride, long cStride,
                                               int maskStride, float scale) {
    // ---- bijective XCD swizzle: hardware order p -> work id w ----
    const int gx = gridDim.x, gy = gridDim.y;
    const int nwg = gx * gy * (int)gridDim.z;
    const int p = ((int)blockIdx.z * gy + (int)blockIdx.y) * gx + (int)blockIdx.x;
    const int qch = nwg >> 3, rch = nwg & 7;
    const int xcd = p & 7, ooff = p >> 3;
    const int w = (xcd < rch ? xcd * (qch + 1) : rch * (qch + 1) + (xcd - rch) * qch) + ooff;
    const int b = w / (gx * gy);
    const int rem = w - b * (gx * gy);
    const int my = rem / gx;
    const int nx = rem - my * gx;
    const int m0 = my * 128;
    const int n0 = nx * 128;

    __shared__ unsigned short As[128 * 32];
    __shared__ unsigned short Bs[128 * 32];

    const int tid = threadIdx.x;
    const int lane = tid & 63, wave = tid >> 6;
    const int wm = wave >> 1, wn = wave & 1;
    const int lrow = lane & 15, quad = lane >> 4;

    // async staging: call j covers rows j*64 + tid>>2, col (tid&3)*8 (16 B)
    const int ar = tid >> 2, ac = (tid & 3) * 8;

    const unsigned short* Ab = Aall + (size_t)b * aStride + (size_t)m0 * lda;
    const unsigned short* Bb = Ball + (size_t)b * bStride + (size_t)n0 * ldb;
    unsigned short* AsW = As + wave * 512;   // wave-uniform async dst
    unsigned short* BsW = Bs + wave * 512;

    f32x4 acc[4][4];
#pragma unroll
    for (int mi = 0; mi < 4; mi++)
#pragma unroll
        for (int ni = 0; ni < 4; ni++)
            acc[mi][ni] = (f32x4){0.f, 0.f, 0.f, 0.f};

    for (int kk = 0; kk < Kred; kk += 32) {
#pragma unroll
        for (int j = 0; j < 2; j++)
            async16(Ab + (size_t)(j * 64 + ar) * lda + kk + ac, AsW + j * 2048);
#pragma unroll
        for (int j = 0; j < 2; j++)
            async16(Bb + (size_t)(j * 64 + ar) * ldb + kk + ac, BsW + j * 2048);
        __syncthreads();

        f16x8 af[4], bfr[4];
#pragma unroll
        for (int i = 0; i < 4; i++)
            af[i] = *(const f16x8*)&As[(wm * 64 + i * 16 + lrow) * 32 + quad * 8];
#pragma unroll
        for (int i = 0; i < 4; i++)
            bfr[i] = *(const f16x8*)&Bs[(wn * 64 + i * 16 + lrow) * 32 + quad * 8];

#pragma unroll
        for (int mi = 0; mi < 4; mi++)
#pragma unroll
            for (int ni = 0; ni < 4; ni++)
                acc[mi][ni] = __builtin_amdgcn_mfma_f32_16x16x32_f16(af[mi], bfr[ni],
                                                                     acc[mi][ni], 0, 0, 0);
        __syncthreads();
    }

    // ---- epilogue ----
#pragma unroll
    for (int mi = 0; mi < 4; mi++) {
        const int gm = m0 + wm * 64 + mi * 16 + quad * 4;
        if constexpr (OUTM == 0) {
            unsigned short* C = (unsigned short*)Call + (size_t)b * cStride;
#pragma unroll
            for (int ni = 0; ni < 4; ni++) {
                int gn = n0 + wn * 64 + ni * 16 + lrow;
#pragma unroll
                for (int r = 0; r < 4; r++)
                    C[(size_t)(gm + r) * ldc + gn] = f2h(acc[mi][ni][r]);
            }
        } else if constexpr (OUTM == 1) {
            unsigned short* C = (unsigned short*)Call + (size_t)b * cStride;
            const int* mk = maskAll + (size_t)b * maskStride;
            float ps[4] = {0.f, 0.f, 0.f, 0.f};
#pragma unroll
            for (int ni = 0; ni < 4; ni++) {
                int gn = n0 + wn * 64 + ni * 16 + lrow;
                bool keep = mk[gn] != 0;
#pragma unroll
                for (int r = 0; r < 4; r++) {
                    float e = keep ? __expf(acc[mi][ni][r] * scale) : 0.f;
                    C[(size_t)(gm + r) * ldc + gn] = f2h(e);
                    ps[r] += e;
                }
            }
            // reduce across the 16 lanes sharing this quad's rows
#pragma unroll
            for (int off = 1; off < 16; off <<= 1)
#pragma unroll
                for (int r = 0; r < 4; r++) ps[r] += __shfl_xor(ps[r], off);
            if (lrow == 0) {
                float* s = sums + (size_t)b * QQ;
#pragma unroll
                for (int r = 0; r < 4; r++) atomicAdd(&s[gm + r], ps[r]);
            }
        } else {
            float* C = (float*)Call + (size_t)b * cStride;
            const float* s = sums + (size_t)b * QQ;
            float iv[4];
#pragma unroll
            for (int r = 0; r < 4; r++) iv[r] = 1.0f / s[gm + r];
#pragma unroll
            for (int ni = 0; ni < 4; ni++) {
                int gn = n0 + wn * 64 + ni * 16 + lrow;
#pragma unroll
                for (int r = 0; r < 4; r++)
                    C[(size_t)(gm + r) * ldc + gn] = acc[mi][ni][r] * iv[r];
            }
        }
    }
}

// ---------------------------------------------------------------------------
// dist[row,:] = expS[row,:] * (1/sums[row]).  One block per row of 2048.
// ---------------------------------------------------------------------------
__global__ __launch_bounds__(256) void normalize_rows(const unsigned short* __restrict__ expS,
                                                      const float* __restrict__ sums,
                                                      float* __restrict__ dist) {
    const unsigned short* sp = expS + (size_t)blockIdx.x * 2048;
    float* dp = dist + (size_t)blockIdx.x * 2048;
    const float inv = 1.0f / sums[blockIdx.x];
    int tid = threadIdx.x;

    uint4 u = *(const uint4*)(sp + tid * 8);
    float4 o0, o1;
    o0.x = h2f((unsigned short)(u.x & 0xffff)) * inv;
    o0.y = h2f((unsigned short)(u.x >> 16)) * inv;
    o0.z = h2f((unsigned short)(u.y & 0xffff)) * inv;
    o0.w = h2f((unsigned short)(u.y >> 16)) * inv;
    o1.x = h2f((unsigned short)(u.z & 0xffff)) * inv;
    o1.y = h2f((unsigned short)(u.z >> 16)) * inv;
    o1.z = h2f((unsigned short)(u.w & 0xffff)) * inv;
    o1.w = h2f((unsigned short)(u.w >> 16)) * inv;
    *(float4*)(dp + tid * 8) = o0;
    *(float4*)(dp + tid * 8 + 4) = o1;
}

// ---------------------------------------------------------------------------
extern "C" void kernel_launch(void* const* d_in, const int* in_sizes, int n_in,
                              void* d_out, int out_size, void* d_ws, size_t ws_size,
                              hipStream_t stream) {
    const float* q    = (const float*)d_in[0];   // [B,Q,D]
    const float* k    = (const float*)d_in[1];   // [B,K,D]
    const float* v    = (const float*)d_in[2];   // [B,K,D]
    const int*   mask = (const int*)d_in[3];     // [B,K]
    const float* W    = (const float*)d_in[4];   // [D,D]

    float* ctx  = (float*)d_out;                           // [B,Q,D]
    float* dist = ctx + (size_t)BB * QQ * DD;              // [B,Q,K]

    // workspace layout (f16 = unsigned short), ~135 MiB
    unsigned short* ws  = (unsigned short*)d_ws;
    unsigned short* Wt  = ws;                                   // [D][D]   (W^T)
    unsigned short* Qh  = Wt + (size_t)DD * DD;                 // [B][Q][D]
    unsigned short* Kh  = Qh + (size_t)BB * QQ * DD;            // [B][K][D]
    unsigned short* Vt  = Kh + (size_t)BB * KK * DD;            // [B][D][K] (V^T)
    unsigned short* qWh = Vt + (size_t)BB * DD * KK;            // [B][Q][D]
    unsigned short* Sc  = qWh + (size_t)BB * QQ * DD;           // [B][Q][K] expS f16
    float* sums = (float*)(Sc + (size_t)BB * QQ * KK);          // [B][Q]

    const float scale = 0.044194173824159216f;  // 1/sqrt(512)

    // 0) zero the row-sum accumulators (graph-capture-legal async memset)
    (void)hipMemsetAsync(sums, 0, (size_t)BB * QQ * sizeof(float), stream);
    // 1) W -> W^T f16
    transpose_cvt<<<dim3(DD / 32, DD / 32, 1), 256, 0, stream>>>(W, Wt, DD, DD, 0, 0);
    // 2) query, key -> f16
    cvt_f32_f16<<<dim3((BB * QQ * DD / 8) / 256), 256, 0, stream>>>(q, Qh);
    cvt_f32_f16<<<dim3((BB * KK * DD / 8) / 256), 256, 0, stream>>>(k, Kh);
    // 3) value -> V^T f16
    transpose_cvt<<<dim3(DD / 32, KK / 32, BB), 256, 0, stream>>>(
        v, Vt, KK, DD, (long)KK * DD, (long)DD * KK);
    // 4) qW[b] = Q[b] @ W: M=Q, N=D, Kred=D -> f16
    gemm_bt<0><<<dim3(DD / 128, QQ / 128, BB), 256, 0, stream>>>(
        Qh, Wt, qWh, nullptr, nullptr, DD, DD, DD, DD,
        (long)QQ * DD, 0, (long)QQ * DD, 0, 0.f);
    // 5) expS[b] = exp(scale * qW[b] @ key[b]^T) (masked->0) + row sums
    gemm_bt<1><<<dim3(KK / 128, QQ / 128, BB), 256, 0, stream>>>(
        qWh, Kh, Sc, mask, sums, DD, DD, DD, KK,
        (long)QQ * DD, (long)KK * DD, (long)QQ * KK, KK, scale);
    // 6) dist = expS / rowsum  (fp32 output)
    normalize_rows<<<dim3(BB * QQ), 256, 0, stream>>>(Sc, sums, dist);
    // 7) context[b] = (expS[b] @ value[b]) / rowsum: M=Q, N=D, Kred=K
    gemm_bt<2><<<dim3(DD / 128, QQ / 128, BB), 256, 0, stream>>>(
        Sc, Vt, ctx, nullptr, sums, KK, KK, KK, DD,
        (long)QQ * KK, (long)DD * KK, (long)QQ * DD, 0, 0.f);
}

// Round 5
// 414.067 us; speedup vs baseline: 1.3007x; 1.0199x over previous
//
#include <hip/hip_runtime.h>
#include <stdint.h>

// Problem constants (reference: B=8, Q=2048, K=2048, D=512)
#define BB 8
#define QQ 2048
#define KK 2048
#define DD 512

typedef _Float16 f16x8 __attribute__((ext_vector_type(8)));
typedef float f32x4 __attribute__((ext_vector_type(4)));

__device__ __forceinline__ unsigned short f2h(float f) {
    union { _Float16 h; unsigned short u; } x;
    x.h = (_Float16)f;
    return x.u;
}
__device__ __forceinline__ float h2f(unsigned short u) {
    union { unsigned short u; _Float16 h; } x;
    x.u = u;
    return (float)x.h;
}

// async global->LDS, 16 B per lane; lds is wave-uniform base, HW scatters
// lane l to lds + l*16 (m97/m104 semantics).
__device__ __forceinline__ void async16(const unsigned short* g, unsigned short* l) {
    __builtin_amdgcn_global_load_lds(
        (const __attribute__((address_space(1))) unsigned int*)g,
        (__attribute__((address_space(3))) unsigned int*)l, 16, 0, 0);
}

// ---------------------------------------------------------------------------
// fp32 -> fp16 convert, 8 elems/thread
// ---------------------------------------------------------------------------
__global__ __launch_bounds__(256) void cvt_f32_f16(const float* __restrict__ in,
                                                   unsigned short* __restrict__ out) {
    size_t i = ((size_t)blockIdx.x * 256 + threadIdx.x) * 8;
    float4 a = *(const float4*)(in + i);
    float4 b = *(const float4*)(in + i + 4);
    uint4 u;
    u.x = (unsigned)f2h(a.x) | ((unsigned)f2h(a.y) << 16);
    u.y = (unsigned)f2h(a.z) | ((unsigned)f2h(a.w) << 16);
    u.z = (unsigned)f2h(b.x) | ((unsigned)f2h(b.y) << 16);
    u.w = (unsigned)f2h(b.z) | ((unsigned)f2h(b.w) << 16);
    *(uint4*)(out + i) = u;
}

// ---------------------------------------------------------------------------
// Tiled transpose + convert: in[R][C] fp32 -> out[C][R] fp16 (32x32 tiles)
// ---------------------------------------------------------------------------
__global__ __launch_bounds__(256) void transpose_cvt(const float* __restrict__ in,
                                                     unsigned short* __restrict__ out,
                                                     int R, int C, long inB, long outB) {
    __shared__ float t[32][33];
    const float* ip = in + (size_t)blockIdx.z * inB;
    unsigned short* op = out + (size_t)blockIdx.z * outB;
    int x = threadIdx.x & 31, y0 = threadIdx.x >> 5;   // 32 x 8
    int c0 = blockIdx.x * 32, r0 = blockIdx.y * 32;
#pragma unroll
    for (int i = 0; i < 32; i += 8)
        t[y0 + i][x] = ip[(size_t)(r0 + y0 + i) * C + c0 + x];
    __syncthreads();
#pragma unroll
    for (int i = 0; i < 32; i += 8)
        op[(size_t)(c0 + y0 + i) * R + r0 + x] = f2h(t[x][y0 + i]);
}

// ---------------------------------------------------------------------------
// Legacy NT GEMM (m97 structure): 128x128 tile, BK=32. Used for OUTM 0 and 2.
// ---------------------------------------------------------------------------
template <int OUTM>
__global__ __launch_bounds__(256) void gemm_bt(const unsigned short* __restrict__ Aall,
                                               const unsigned short* __restrict__ Ball,
                                               void* __restrict__ Call,
                                               const int* __restrict__ maskAll,
                                               float* __restrict__ sums,
                                               int Kred, int lda, int ldb, int ldc,
                                               long aStride, long bStride, long cStride,
                                               int maskStride, float scale) {
    // ---- bijective XCD swizzle: hardware order p -> work id w ----
    const int gx = gridDim.x, gy = gridDim.y;
    const int nwg = gx * gy * (int)gridDim.z;
    const int p = ((int)blockIdx.z * gy + (int)blockIdx.y) * gx + (int)blockIdx.x;
    const int qch = nwg >> 3, rch = nwg & 7;
    const int xcd = p & 7, ooff = p >> 3;
    const int w = (xcd < rch ? xcd * (qch + 1) : rch * (qch + 1) + (xcd - rch) * qch) + ooff;
    const int b = w / (gx * gy);
    const int rem = w - b * (gx * gy);
    const int my = rem / gx;
    const int nx = rem - my * gx;
    const int m0 = my * 128;
    const int n0 = nx * 128;

    __shared__ unsigned short As[128 * 32];
    __shared__ unsigned short Bs[128 * 32];

    const int tid = threadIdx.x;
    const int lane = tid & 63, wave = tid >> 6;
    const int wm = wave >> 1, wn = wave & 1;
    const int lrow = lane & 15, quad = lane >> 4;

    const int ar = tid >> 2, ac = (tid & 3) * 8;

    const unsigned short* Ab = Aall + (size_t)b * aStride + (size_t)m0 * lda;
    const unsigned short* Bb = Ball + (size_t)b * bStride + (size_t)n0 * ldb;
    unsigned short* AsW = As + wave * 512;   // wave-uniform async dst
    unsigned short* BsW = Bs + wave * 512;

    f32x4 acc[4][4];
#pragma unroll
    for (int mi = 0; mi < 4; mi++)
#pragma unroll
        for (int ni = 0; ni < 4; ni++)
            acc[mi][ni] = (f32x4){0.f, 0.f, 0.f, 0.f};

    for (int kk = 0; kk < Kred; kk += 32) {
#pragma unroll
        for (int j = 0; j < 2; j++)
            async16(Ab + (size_t)(j * 64 + ar) * lda + kk + ac, AsW + j * 2048);
#pragma unroll
        for (int j = 0; j < 2; j++)
            async16(Bb + (size_t)(j * 64 + ar) * ldb + kk + ac, BsW + j * 2048);
        __syncthreads();

        f16x8 af[4], bfr[4];
#pragma unroll
        for (int i = 0; i < 4; i++)
            af[i] = *(const f16x8*)&As[(wm * 64 + i * 16 + lrow) * 32 + quad * 8];
#pragma unroll
        for (int i = 0; i < 4; i++)
            bfr[i] = *(const f16x8*)&Bs[(wn * 64 + i * 16 + lrow) * 32 + quad * 8];

#pragma unroll
        for (int mi = 0; mi < 4; mi++)
#pragma unroll
            for (int ni = 0; ni < 4; ni++)
                acc[mi][ni] = __builtin_amdgcn_mfma_f32_16x16x32_f16(af[mi], bfr[ni],
                                                                     acc[mi][ni], 0, 0, 0);
        __syncthreads();
    }

#pragma unroll
    for (int mi = 0; mi < 4; mi++) {
        const int gm = m0 + wm * 64 + mi * 16 + quad * 4;
        if constexpr (OUTM == 0) {
            unsigned short* C = (unsigned short*)Call + (size_t)b * cStride;
#pragma unroll
            for (int ni = 0; ni < 4; ni++) {
                int gn = n0 + wn * 64 + ni * 16 + lrow;
#pragma unroll
                for (int r = 0; r < 4; r++)
                    C[(size_t)(gm + r) * ldc + gn] = f2h(acc[mi][ni][r]);
            }
        } else {
            float* C = (float*)Call + (size_t)b * cStride;
            const float* s = sums + (size_t)b * QQ;
            float iv[4];
#pragma unroll
            for (int r = 0; r < 4; r++) iv[r] = 1.0f / s[gm + r];
#pragma unroll
            for (int ni = 0; ni < 4; ni++) {
                int gn = n0 + wn * 64 + ni * 16 + lrow;
#pragma unroll
                for (int r = 0; r < 4; r++)
                    C[(size_t)(gm + r) * ldc + gn] = acc[mi][ni][r] * iv[r];
            }
        }
    }
}

// ---------------------------------------------------------------------------
// Deep-pipelined 256x256 NT GEMM with exp/mask/rowsum epilogue (scores step).
// 8 waves (2M x 4N), BK=32, quad-buffered LDS ring (4 slots, 128 KiB total),
// prefetch distance 3 K-tiles, counted s_waitcnt vmcnt gates (never 0 in
// steady state), ONE raw s_barrier per K-tile, 2 phases x 16 MFMA with
// s_setprio around each MFMA cluster.
// LDS bank-conflict fix (both-sides, rule #21): 16B-slot XOR swizzle
//   LDS[r][s] = G[r][s ^ ((r>>1)&3)]
// via pre-swizzled per-lane GLOBAL source (LDS dst stays linear for
// global_load_lds) + swizzled ds_read slot. (row>>1)-based XOR makes the
// (row parity, slot) pairs cover all 8 half-row bank groups exactly twice
// -> 2-way aliasing = free (m136).
// ---------------------------------------------------------------------------
__global__ __launch_bounds__(512, 2) void gemm256_exp(
    const unsigned short* __restrict__ Aall, const unsigned short* __restrict__ Ball,
    unsigned short* __restrict__ Call, const int* __restrict__ maskAll,
    float* __restrict__ sums, int Kred, int lda, int ldb, int ldc,
    long aStride, long bStride, long cStride, int maskStride, float scale) {
    // ---- bijective XCD swizzle ----
    const int gx = gridDim.x, gy = gridDim.y;
    const int nwg = gx * gy * (int)gridDim.z;
    const int p = ((int)blockIdx.z * gy + (int)blockIdx.y) * gx + (int)blockIdx.x;
    const int qch = nwg >> 3, rch = nwg & 7;
    const int xcd = p & 7, ooff = p >> 3;
    const int w = (xcd < rch ? xcd * (qch + 1) : rch * (qch + 1) + (xcd - rch) * qch) + ooff;
    const int b = w / (gx * gy);
    const int rem = w - b * (gx * gy);
    const int my = rem / gx;
    const int nx = rem - my * gx;
    const int m0 = my * 256;
    const int n0 = nx * 256;

    __shared__ unsigned short As[4][256 * 32];   // 64 KiB ring (4 slots)
    __shared__ unsigned short Bs[4][256 * 32];   // 64 KiB ring

    const int tid = threadIdx.x;
    const int lane = tid & 63, wv = tid >> 6;    // 8 waves
    const int wm = wv >> 2, wn = wv & 3;         // 2 x 4 wave grid
    const int lrow = lane & 15, quad = lane >> 4;

    // staging: per wave, call j covers a 1-KiB chunk = 16 rows x 64 B.
    // lane l -> row sr = l>>2 (within chunk), slot l&3 (HW-linear LDS write).
    // Pre-swizzled global slot: ssl = (l&3) ^ ((sr>>1)&3).
    const int sr = lane >> 2;
    const int ssl = (lane & 3) ^ ((sr >> 1) & 3);
    const unsigned short* Ab = Aall + (size_t)b * aStride + (size_t)m0 * lda;
    const unsigned short* Bb = Ball + (size_t)b * bStride + (size_t)n0 * ldb;

    const int NT = Kred >> 5;                    // K-tiles of 32

    auto stageA = [&](int t) {
#pragma unroll
        for (int j = 0; j < 2; j++) {
            const int c = wv * 2 + j;            // chunk 0..15
            const int r = c * 16 + sr;           // tile row 0..255
            async16(Ab + (size_t)r * lda + t * 32 + ssl * 8,
                    &As[t & 3][c * 512]);        // 512 shorts = 1 KiB per chunk
        }
    };
    auto stageB = [&](int t) {
#pragma unroll
        for (int j = 0; j < 2; j++) {
            const int c = wv * 2 + j;
            const int r = c * 16 + sr;
            async16(Bb + (size_t)r * ldb + t * 32 + ssl * 8,
                    &Bs[t & 3][c * 512]);
        }
    };

    f32x4 acc[8][4];
#pragma unroll
    for (int mi = 0; mi < 8; mi++)
#pragma unroll
        for (int ni = 0; ni < 4; ni++)
            acc[mi][ni] = (f32x4){0.f, 0.f, 0.f, 0.f};

    // prologue: stage tiles 0..2 (12 loads/wave in flight)
    for (int tt = 0; tt < 3 && tt < NT; ++tt) { stageA(tt); stageB(tt); }

    const int rsw = (lrow >> 1) & 3;   // read-side slot XOR for fragment rows

    for (int t = 0; t < NT; ++t) {
        // gate: tile t's 4 loads (oldest in this wave's FIFO) must be retired
        if (t + 2 < NT)      asm volatile("s_waitcnt vmcnt(8)" ::: "memory");
        else if (t + 1 < NT) asm volatile("s_waitcnt vmcnt(4)" ::: "memory");
        else                 asm volatile("s_waitcnt vmcnt(0)" ::: "memory");
        __builtin_amdgcn_s_barrier();
        __builtin_amdgcn_sched_barrier(0);       // pin ds_reads below barrier

        const unsigned short* Asl = As[t & 3];
        const unsigned short* Bsl = Bs[t & 3];
        f16x8 af[4], bfr[4];

        // ---- phase 0: stage A(t+3) | read B-frags + A-frags 0-3 | 16 MFMA ----
        if (t + 3 < NT) stageA(t + 3);
#pragma unroll
        for (int ni = 0; ni < 4; ni++)
            bfr[ni] = *(const f16x8*)&Bsl[(wn * 64 + ni * 16 + lrow) * 32 + ((quad ^ rsw) * 8)];
#pragma unroll
        for (int mi = 0; mi < 4; mi++)
            af[mi] = *(const f16x8*)&Asl[(wm * 128 + mi * 16 + lrow) * 32 + ((quad ^ rsw) * 8)];
        __builtin_amdgcn_s_setprio(1);
#pragma unroll
        for (int mi = 0; mi < 4; mi++)
#pragma unroll
            for (int ni = 0; ni < 4; ni++)
                acc[mi][ni] = __builtin_amdgcn_mfma_f32_16x16x32_f16(af[mi], bfr[ni],
                                                                     acc[mi][ni], 0, 0, 0);
        __builtin_amdgcn_s_setprio(0);

        // ---- phase 1: stage B(t+3) | read A-frags 4-7 | 16 MFMA ----
        if (t + 3 < NT) stageB(t + 3);
#pragma unroll
        for (int mi = 0; mi < 4; mi++)
            af[mi] = *(const f16x8*)&Asl[(wm * 128 + (mi + 4) * 16 + lrow) * 32 + ((quad ^ rsw) * 8)];
        __builtin_amdgcn_s_setprio(1);
#pragma unroll
        for (int mi = 0; mi < 4; mi++)
#pragma unroll
            for (int ni = 0; ni < 4; ni++)
                acc[mi + 4][ni] = __builtin_amdgcn_mfma_f32_16x16x32_f16(af[mi], bfr[ni],
                                                                         acc[mi + 4][ni], 0, 0, 0);
        __builtin_amdgcn_s_setprio(0);
    }

    // ---- epilogue: e = mask ? exp(acc*scale) : 0 -> f16 out; rowsum atomics ----
    unsigned short* C = Call + (size_t)b * cStride;
    const int* mk = maskAll + (size_t)b * maskStride;
#pragma unroll
    for (int mi = 0; mi < 8; mi++) {
        const int gm = m0 + wm * 128 + mi * 16 + quad * 4;
        float ps[4] = {0.f, 0.f, 0.f, 0.f};
#pragma unroll
        for (int ni = 0; ni < 4; ni++) {
            int gn = n0 + wn * 64 + ni * 16 + lrow;
            bool keep = mk[gn] != 0;
#pragma unroll
            for (int r = 0; r < 4; r++) {
                float e = keep ? __expf(acc[mi][ni][r] * scale) : 0.f;
                C[(size_t)(gm + r) * ldc + gn] = f2h(e);
                ps[r] += e;
            }
        }
#pragma unroll
        for (int off = 1; off < 16; off <<= 1)
#pragma unroll
            for (int r = 0; r < 4; r++) ps[r] += __shfl_xor(ps[r], off);
        if (lrow == 0) {
            float* s = sums + (size_t)b * QQ;
#pragma unroll
            for (int r = 0; r < 4; r++) atomicAdd(&s[gm + r], ps[r]);
        }
    }
}

// ---------------------------------------------------------------------------
// dist[row,:] = expS[row,:] * (1/sums[row]).  One block per row of 2048.
// ---------------------------------------------------------------------------
__global__ __launch_bounds__(256) void normalize_rows(const unsigned short* __restrict__ expS,
                                                      const float* __restrict__ sums,
                                                      float* __restrict__ dist) {
    const unsigned short* sp = expS + (size_t)blockIdx.x * 2048;
    float* dp = dist + (size_t)blockIdx.x * 2048;
    const float inv = 1.0f / sums[blockIdx.x];
    int tid = threadIdx.x;

    uint4 u = *(const uint4*)(sp + tid * 8);
    float4 o0, o1;
    o0.x = h2f((unsigned short)(u.x & 0xffff)) * inv;
    o0.y = h2f((unsigned short)(u.x >> 16)) * inv;
    o0.z = h2f((unsigned short)(u.y & 0xffff)) * inv;
    o0.w = h2f((unsigned short)(u.y >> 16)) * inv;
    o1.x = h2f((unsigned short)(u.z & 0xffff)) * inv;
    o1.y = h2f((unsigned short)(u.z >> 16)) * inv;
    o1.z = h2f((unsigned short)(u.w & 0xffff)) * inv;
    o1.w = h2f((unsigned short)(u.w >> 16)) * inv;
    *(float4*)(dp + tid * 8) = o0;
    *(float4*)(dp + tid * 8 + 4) = o1;
}

// ---------------------------------------------------------------------------
extern "C" void kernel_launch(void* const* d_in, const int* in_sizes, int n_in,
                              void* d_out, int out_size, void* d_ws, size_t ws_size,
                              hipStream_t stream) {
    const float* q    = (const float*)d_in[0];   // [B,Q,D]
    const float* k    = (const float*)d_in[1];   // [B,K,D]
    const float* v    = (const float*)d_in[2];   // [B,K,D]
    const int*   mask = (const int*)d_in[3];     // [B,K]
    const float* W    = (const float*)d_in[4];   // [D,D]

    float* ctx  = (float*)d_out;                           // [B,Q,D]
    float* dist = ctx + (size_t)BB * QQ * DD;              // [B,Q,K]

    // workspace layout (f16 = unsigned short), ~135 MiB
    unsigned short* ws  = (unsigned short*)d_ws;
    unsigned short* Wt  = ws;                                   // [D][D]   (W^T)
    unsigned short* Qh  = Wt + (size_t)DD * DD;                 // [B][Q][D]
    unsigned short* Kh  = Qh + (size_t)BB * QQ * DD;            // [B][K][D]
    unsigned short* Vt  = Kh + (size_t)BB * KK * DD;            // [B][D][K] (V^T)
    unsigned short* qWh = Vt + (size_t)BB * DD * KK;            // [B][Q][D]
    unsigned short* Sc  = qWh + (size_t)BB * QQ * DD;           // [B][Q][K] expS f16
    float* sums = (float*)(Sc + (size_t)BB * QQ * KK);          // [B][Q]

    const float scale = 0.044194173824159216f;  // 1/sqrt(512)

    // 0) zero the row-sum accumulators (graph-capture-legal async memset)
    (void)hipMemsetAsync(sums, 0, (size_t)BB * QQ * sizeof(float), stream);
    // 1) W -> W^T f16
    transpose_cvt<<<dim3(DD / 32, DD / 32, 1), 256, 0, stream>>>(W, Wt, DD, DD, 0, 0);
    // 2) query, key -> f16
    cvt_f32_f16<<<dim3((BB * QQ * DD / 8) / 256), 256, 0, stream>>>(q, Qh);
    cvt_f32_f16<<<dim3((BB * KK * DD / 8) / 256), 256, 0, stream>>>(k, Kh);
    // 3) value -> V^T f16
    transpose_cvt<<<dim3(DD / 32, KK / 32, BB), 256, 0, stream>>>(
        v, Vt, KK, DD, (long)KK * DD, (long)DD * KK);
    // 4) qW[b] = Q[b] @ W: M=Q, N=D, Kred=D -> f16
    gemm_bt<0><<<dim3(DD / 128, QQ / 128, BB), 256, 0, stream>>>(
        Qh, Wt, qWh, nullptr, nullptr, DD, DD, DD, DD,
        (long)QQ * DD, 0, (long)QQ * DD, 0, 0.f);
    // 5) expS[b] = exp(scale * qW[b] @ key[b]^T) (masked->0) + row sums
    //    256x256-tile deep-pipelined kernel
    gemm256_exp<<<dim3(KK / 256, QQ / 256, BB), 512, 0, stream>>>(
        qWh, Kh, Sc, mask, sums, DD, DD, DD, KK,
        (long)QQ * DD, (long)KK * DD, (long)QQ * KK, KK, scale);
    // 6) dist = expS / rowsum  (fp32 output)
    normalize_rows<<<dim3(BB * QQ), 256, 0, stream>>>(Sc, sums, dist);
    // 7) context[b] = (expS[b] @ value[b]) / rowsum: M=Q, N=D, Kred=K
    gemm_bt<2><<<dim3(DD / 128, QQ / 128, BB), 256, 0, stream>>>(
        Sc, Vt, ctx, nullptr, sums, KK, KK, KK, DD,
        (long)QQ * KK, (long)DD * KK, (long)QQ * DD, 0, 0.f);
}